// Round 1
// baseline (1584.703 us; speedup 1.0000x reference)
//
#include <hip/hip_runtime.h>
#include <hip/hip_bf16.h>
#include <math.h>

// Problem constants (fixed by setup_inputs)
#define B_ 64
#define T_ 32
#define H_ 1024
#define V_ 32000
#define M_ (B_ * T_)   // 2048

typedef __attribute__((ext_vector_type(8))) short short8;
typedef __attribute__((ext_vector_type(4))) float f32x4;

__device__ __forceinline__ unsigned short f2bf(float f) {
  unsigned u = __float_as_uint(f);
  u = (u + 0x7FFFu + ((u >> 16) & 1u)) >> 16;   // RNE
  return (unsigned short)u;
}

__device__ __forceinline__ void async16(const void* g, void* l) {
  __builtin_amdgcn_global_load_lds(
      (const __attribute__((address_space(1))) unsigned int*)g,
      (__attribute__((address_space(3))) unsigned int*)l, 16, 0, 0);
}

// ---------------- f32 -> bf16 weight conversion (8 elts/thread) ----------------
__global__ void k_convert(const float* __restrict__ src, short* __restrict__ dst, int n8) {
  int i = blockIdx.x * blockDim.x + threadIdx.x;
  if (i >= n8) return;
  const f32x4* s = (const f32x4*)src + (size_t)i * 2;
  f32x4 a = s[0], b = s[1];
  short8 o;
  o[0] = (short)f2bf(a[0]); o[1] = (short)f2bf(a[1]);
  o[2] = (short)f2bf(a[2]); o[3] = (short)f2bf(a[3]);
  o[4] = (short)f2bf(b[0]); o[5] = (short)f2bf(b[1]);
  o[6] = (short)f2bf(b[2]); o[7] = (short)f2bf(b[3]);
  *((short8*)dst + i) = o;
}

// ---------------- embedding gather + relu + bf16; h0 init ----------------
// blocks [0,2048): x rows (m = t*64+b).  blocks [2048,2112): h0 rows.
__global__ void k_embed(const float* __restrict__ emb, const int* __restrict__ tgt,
                        const int* __restrict__ sos, const float* __restrict__ ehid,
                        short* __restrict__ xb, float* __restrict__ hf, short* __restrict__ hb) {
  int m = blockIdx.x, tid = threadIdx.x;  // 128 threads, 8 elts each
  if (m < M_) {
    int t = m >> 6, b = m & 63;
    int token = (t == 0) ? sos[0] : tgt[b * T_ + (t - 1)];
    const f32x4* s = (const f32x4*)(emb + (size_t)token * H_) + tid * 2;
    f32x4 a = s[0], c = s[1];
    short8 o;
    #pragma unroll
    for (int j = 0; j < 4; ++j) { float v = a[j] > 0.f ? a[j] : 0.f; o[j] = (short)f2bf(v); }
    #pragma unroll
    for (int j = 0; j < 4; ++j) { float v = c[j] > 0.f ? c[j] : 0.f; o[4 + j] = (short)f2bf(v); }
    *((short8*)(xb + (size_t)m * H_) + tid) = o;
  } else {
    int b = m - M_;
    const f32x4* s = (const f32x4*)(ehid + (size_t)b * H_) + tid * 2;
    f32x4 a = s[0], c = s[1];
    f32x4* fo = (f32x4*)(hf + (size_t)b * H_) + tid * 2;
    fo[0] = a; fo[1] = c;
    short8 o;
    #pragma unroll
    for (int j = 0; j < 4; ++j) o[j] = (short)f2bf(a[j]);
    #pragma unroll
    for (int j = 0; j < 4; ++j) o[4 + j] = (short)f2bf(c[j]);
    *((short8*)(hb + (size_t)b * H_) + tid) = o;
  }
}

// ---------------- 128x128 bf16 MFMA GEMM, K=1024, BK=64 ----------------
// C[m][n] = sum_k A[m][k]*B[n][k] + bias[n].  A,B row-major K-contiguous bf16.
// do_exp: also atomicAdd per-row sum of exp(C) into sumexp (max-free logsumexp;
// |logit| <= ~18 so f32 exp is safe).
// LDS tiles [128 rows][8 granules of 8 bf16], granule col XOR-swizzled with (row&7)
// -> conflict-free ds_read_b128 while keeping global_load_lds lane-contiguous dest.
__global__ __launch_bounds__(256, 2)
void k_gemm(const short* __restrict__ A, const short* __restrict__ Bm,
            const float* __restrict__ bias, float* __restrict__ C,
            float* __restrict__ sumexp, int N, int do_exp) {
  __shared__ short As[128 * 64];
  __shared__ short Bs[128 * 64];
  const int tid = threadIdx.x;
  const int bn = blockIdx.x, bm = blockIdx.y;
  const int w = tid >> 6, l = tid & 63;
  const int wm = (w >> 1) * 64, wn = (w & 1) * 64;
  f32x4 acc[4][4] = {};
  const short* Ab = A + (size_t)(bm * 128) * 1024;
  const short* Bb = Bm + (size_t)(bn * 128) * 1024;

  for (int kt = 0; kt < 1024; kt += 64) {
    #pragma unroll
    for (int i = 0; i < 4; ++i) {
      int g = i * 256 + tid, r = g >> 3, cp = g & 7, c = cp ^ (r & 7);
      async16(Ab + r * 1024 + kt + c * 8, &As[g * 8]);
    }
    #pragma unroll
    for (int i = 0; i < 4; ++i) {
      int g = i * 256 + tid, r = g >> 3, cp = g & 7, c = cp ^ (r & 7);
      async16(Bb + r * 1024 + kt + c * 8, &Bs[g * 8]);
    }
    __syncthreads();
    #pragma unroll
    for (int ks = 0; ks < 2; ++ks) {
      short8 af[4], bf[4];
      #pragma unroll
      for (int mi = 0; mi < 4; ++mi) {
        int row = wm + mi * 16 + (l & 15);
        int cp = (ks * 4 + (l >> 4)) ^ (row & 7);
        af[mi] = *(const short8*)&As[row * 64 + cp * 8];
      }
      #pragma unroll
      for (int ni = 0; ni < 4; ++ni) {
        int row = wn + ni * 16 + (l & 15);
        int cp = (ks * 4 + (l >> 4)) ^ (row & 7);
        bf[ni] = *(const short8*)&Bs[row * 64 + cp * 8];
      }
      #pragma unroll
      for (int mi = 0; mi < 4; ++mi)
        #pragma unroll
        for (int ni = 0; ni < 4; ++ni)
          acc[mi][ni] = __builtin_amdgcn_mfma_f32_16x16x32_bf16(af[mi], bf[ni], acc[mi][ni], 0, 0, 0);
    }
    __syncthreads();
  }

  // C/D layout: col = lane&15, row = (lane>>4)*4 + reg   [m89-verified]
  const int row0 = bm * 128 + wm + (l >> 4) * 4;
  const int col0 = bn * 128 + wn + (l & 15);
  if (!do_exp) {
    #pragma unroll
    for (int mi = 0; mi < 4; ++mi)
      #pragma unroll
      for (int ni = 0; ni < 4; ++ni) {
        int col = col0 + ni * 16;
        float bv = bias[col];
        #pragma unroll
        for (int rg = 0; rg < 4; ++rg)
          C[(size_t)(row0 + mi * 16 + rg) * N + col] = acc[mi][ni][rg] + bv;
      }
  } else {
    #pragma unroll
    for (int mi = 0; mi < 4; ++mi) {
      float rs[4] = {0.f, 0.f, 0.f, 0.f};
      #pragma unroll
      for (int ni = 0; ni < 4; ++ni) {
        int col = col0 + ni * 16;
        float bv = bias[col];
        #pragma unroll
        for (int rg = 0; rg < 4; ++rg) {
          float v = acc[mi][ni][rg] + bv;
          C[(size_t)(row0 + mi * 16 + rg) * N + col] = v;
          rs[rg] += __expf(v);
        }
      }
      #pragma unroll
      for (int rg = 0; rg < 4; ++rg) {
        float v = rs[rg];
        #pragma unroll
        for (int off = 1; off < 16; off <<= 1) v += __shfl_xor(v, off, 64);
        if ((l & 15) == 0) atomicAdd(&sumexp[row0 + mi * 16 + rg], v);
      }
    }
  }
}

// ---------------- fused GRU step: gh GEMM (all 3 gates per j-strip) + gates ----------------
// grid = 16 blocks, each owns j in [bn*64, bn*64+64) and computes gh for gates r,z,n
// so the nonlinearity fuses in-register. h_bf16 ping-pongs across steps (cross-block
// RAW: K-loop reads all of h while epilogue writes it).
__global__ __launch_bounds__(256, 2)
void k_gru(const short* __restrict__ hb_in, const short* __restrict__ Whh,
           const float* __restrict__ bhh, const float* __restrict__ gi,
           float* __restrict__ hf, short* __restrict__ hb_out,
           short* __restrict__ hs, float* __restrict__ hfin, int t) {
  __shared__ short As[64 * 64];        // h tile
  __shared__ short Bs[3 * 64 * 64];    // W_hh tiles, one per gate
  const int tid = threadIdx.x;
  const int bn = blockIdx.x;           // j0 = bn*64
  const int w = tid >> 6, l = tid & 63;
  f32x4 acc[3][4] = {};

  for (int kt = 0; kt < 1024; kt += 64) {
    #pragma unroll
    for (int i = 0; i < 2; ++i) {
      int g = i * 256 + tid, r = g >> 3, cp = g & 7, c = cp ^ (r & 7);
      async16(hb_in + r * 1024 + kt + c * 8, &As[g * 8]);
    }
    #pragma unroll
    for (int ga = 0; ga < 3; ++ga)
      #pragma unroll
      for (int i = 0; i < 2; ++i) {
        int g = i * 256 + tid, r = g >> 3, cp = g & 7, c = cp ^ (r & 7);
        async16(Whh + (size_t)(ga * 1024 + bn * 64 + r) * 1024 + kt + c * 8,
                &Bs[ga * 4096 + g * 8]);
      }
    __syncthreads();
    #pragma unroll
    for (int ks = 0; ks < 2; ++ks) {
      short8 af[4], bf[3];
      #pragma unroll
      for (int mi = 0; mi < 4; ++mi) {
        int row = mi * 16 + (l & 15);
        int cp = (ks * 4 + (l >> 4)) ^ (row & 7);
        af[mi] = *(const short8*)&As[row * 64 + cp * 8];
      }
      #pragma unroll
      for (int ga = 0; ga < 3; ++ga) {
        int row = w * 16 + (l & 15);
        int cp = (ks * 4 + (l >> 4)) ^ (row & 7);
        bf[ga] = *(const short8*)&Bs[ga * 4096 + row * 64 + cp * 8];
      }
      #pragma unroll
      for (int ga = 0; ga < 3; ++ga)
        #pragma unroll
        for (int mi = 0; mi < 4; ++mi)
          acc[ga][mi] = __builtin_amdgcn_mfma_f32_16x16x32_bf16(af[mi], bf[ga], acc[ga][mi], 0, 0, 0);
    }
    __syncthreads();
  }

  const int j = bn * 64 + w * 16 + (l & 15);
  const float bh_r = bhh[j], bh_z = bhh[1024 + j], bh_n = bhh[2048 + j];
  #pragma unroll
  for (int mi = 0; mi < 4; ++mi)
    #pragma unroll
    for (int rg = 0; rg < 4; ++rg) {
      int b = mi * 16 + (l >> 4) * 4 + rg;
      const float* gir = gi + (size_t)(t * 64 + b) * 3072;
      float r = gir[j] + acc[0][mi][rg] + bh_r;
      r = 1.f / (1.f + __expf(-r));
      float z = gir[1024 + j] + acc[1][mi][rg] + bh_z;
      z = 1.f / (1.f + __expf(-z));
      float n = gir[2048 + j] + r * (acc[2][mi][rg] + bh_n);
      n = tanhf(n);
      float hp = hf[(size_t)b * H_ + j];
      float hn = (1.f - z) * n + z * hp;
      hf[(size_t)b * H_ + j] = hn;
      short hbv = (short)f2bf(hn);
      hb_out[(size_t)b * H_ + j] = hbv;
      hs[(size_t)(b * T_ + t) * H_ + j] = hbv;   // (b,t)-major for logits GEMM
      if (t == T_ - 1) hfin[(size_t)b * H_ + j] = hn;
    }
}

// ---------------- logsumexp finalize ----------------
__global__ void k_lse(float* s) {
  int i = blockIdx.x * 256 + threadIdx.x;
  if (i < M_) s[i] = logf(s[i]);
}

__global__ void k_sub(float* __restrict__ out, const float* __restrict__ lse) {
  size_t vid = (size_t)blockIdx.x * 256 + threadIdx.x;   // 16,384,000 float4s
  int r = (int)(vid / (V_ / 4));
  float ls = lse[r];
  f32x4* p = (f32x4*)out + vid;
  f32x4 v = *p;
  v[0] -= ls; v[1] -= ls; v[2] -= ls; v[3] -= ls;
  *p = v;
}

extern "C" void kernel_launch(void* const* d_in, const int* in_sizes, int n_in,
                              void* d_out, int out_size, void* d_ws, size_t ws_size,
                              hipStream_t stream) {
  const float* ehid = (const float*)d_in[1];
  const int*   tgt  = (const int*)d_in[3];
  const int*   sos  = (const int*)d_in[4];
  const float* emb  = (const float*)d_in[6];
  const float* Wih  = (const float*)d_in[7];
  const float* Whh  = (const float*)d_in[8];
  const float* bih  = (const float*)d_in[9];
  const float* bhh  = (const float*)d_in[10];
  const float* outW = (const float*)d_in[11];
  const float* outb = (const float*)d_in[12];
  float* out = (float*)d_out;

  // workspace carve-out (~112.3 MB total)
  char* ws = (char*)d_ws;
  size_t off = 0;
  auto alloc = [&](size_t bytes) -> void* {
    void* p = ws + off;
    off = (off + bytes + 255) & ~(size_t)255;
    return p;
  };
  short* outW_b = (short*)alloc((size_t)V_ * H_ * 2);       // 65.5 MB
  short* Wih_b  = (short*)alloc((size_t)3 * H_ * H_ * 2);   // 6.3 MB
  short* Whh_b  = (short*)alloc((size_t)3 * H_ * H_ * 2);   // 6.3 MB
  short* xb     = (short*)alloc((size_t)M_ * H_ * 2);       // 4.2 MB
  float* gi     = (float*)alloc((size_t)M_ * 3 * H_ * 4);   // 25.2 MB
  short* hs     = (short*)alloc((size_t)M_ * H_ * 2);       // 4.2 MB
  float* hf     = (float*)alloc((size_t)B_ * H_ * 4);
  short* hb0    = (short*)alloc((size_t)B_ * H_ * 2);
  short* hb1    = (short*)alloc((size_t)B_ * H_ * 2);
  float* sume   = (float*)alloc((size_t)M_ * 4);

  // weight conversions f32 -> bf16
  k_convert<<<V_ * H_ / 8 / 256, 256, 0, stream>>>(outW, outW_b, V_ * H_ / 8);
  k_convert<<<3 * H_ * H_ / 8 / 256, 256, 0, stream>>>(Wih, Wih_b, 3 * H_ * H_ / 8);
  k_convert<<<3 * H_ * H_ / 8 / 256, 256, 0, stream>>>(Whh, Whh_b, 3 * H_ * H_ / 8);

  // embedding gather + relu + h0 init
  k_embed<<<M_ + B_, 128, 0, stream>>>(emb, tgt, sos, ehid, xb, hf, hb0);

  // gi = relu(emb[tokens]) @ W_ih^T + b_ih   (M=2048, N=3072)
  dim3 g1(3 * H_ / 128, M_ / 128);
  k_gemm<<<g1, 256, 0, stream>>>(xb, Wih_b, bih, gi, nullptr, 3 * H_, 0);

  // GRU recurrence, 32 sequential steps (h_bf16 ping-pong)
  for (int t = 0; t < T_; ++t) {
    const short* hin = (t & 1) ? hb1 : hb0;
    short* hout      = (t & 1) ? hb0 : hb1;
    k_gru<<<16, 256, 0, stream>>>(hin, Whh_b, bhh, gi, hf, hout, hs,
                                  out + (size_t)B_ * T_ * V_, t);
  }

  // logits = hs @ out_W^T + out_b, fused exp-row-sum (M=2048, N=32000)
  hipMemsetAsync(sume, 0, M_ * 4, stream);
  dim3 g2(V_ / 128, M_ / 128);
  k_gemm<<<g2, 256, 0, stream>>>(hs, outW_b, outb, out, sume, V_, 1);

  // log_probs = logits - log(sum exp)
  k_lse<<<8, 256, 0, stream>>>(sume);
  k_sub<<<(int)((size_t)B_ * T_ * V_ / 4 / 256), 256, 0, stream>>>(out, sume);
}

// Round 2
// 1056.937 us; speedup vs baseline: 1.4993x; 1.4993x over previous
//
#include <hip/hip_runtime.h>
#include <hip/hip_bf16.h>
#include <math.h>

// Problem constants (fixed by setup_inputs)
#define B_ 64
#define T_ 32
#define H_ 1024
#define V_ 32000
#define M_ (B_ * T_)   // 2048
#define GRUB 64        // persistent GRU blocks (<=256 CUs -> co-resident)

typedef __attribute__((ext_vector_type(8))) short short8;
typedef __attribute__((ext_vector_type(4))) float f32x4;

__device__ __forceinline__ unsigned short f2bf(float f) {
  unsigned u = __float_as_uint(f);
  u = (u + 0x7FFFu + ((u >> 16) & 1u)) >> 16;   // RNE
  return (unsigned short)u;
}

__device__ __forceinline__ void async16(const void* g, void* l) {
  __builtin_amdgcn_global_load_lds(
      (const __attribute__((address_space(1))) unsigned int*)g,
      (__attribute__((address_space(3))) unsigned int*)l, 16, 0, 0);
}

// ---------------- f32 -> bf16 weight conversion (8 elts/thread) ----------------
__global__ void k_convert(const float* __restrict__ src, short* __restrict__ dst, int n8) {
  int i = blockIdx.x * blockDim.x + threadIdx.x;
  if (i >= n8) return;
  const f32x4* s = (const f32x4*)src + (size_t)i * 2;
  f32x4 a = s[0], b = s[1];
  short8 o;
  o[0] = (short)f2bf(a[0]); o[1] = (short)f2bf(a[1]);
  o[2] = (short)f2bf(a[2]); o[3] = (short)f2bf(a[3]);
  o[4] = (short)f2bf(b[0]); o[5] = (short)f2bf(b[1]);
  o[6] = (short)f2bf(b[2]); o[7] = (short)f2bf(b[3]);
  *((short8*)dst + i) = o;
}

// ---------------- embedding gather + relu + bf16; h0(bf16) init ----------------
__global__ void k_embed(const float* __restrict__ emb, const int* __restrict__ tgt,
                        const int* __restrict__ sos, const float* __restrict__ ehid,
                        short* __restrict__ xb, short* __restrict__ hb) {
  int m = blockIdx.x, tid = threadIdx.x;  // 128 threads, 8 elts each
  if (m < M_) {
    int t = m >> 6, b = m & 63;
    int token = (t == 0) ? sos[0] : tgt[b * T_ + (t - 1)];
    const f32x4* s = (const f32x4*)(emb + (size_t)token * H_) + tid * 2;
    f32x4 a = s[0], c = s[1];
    short8 o;
    #pragma unroll
    for (int j = 0; j < 4; ++j) { float v = a[j] > 0.f ? a[j] : 0.f; o[j] = (short)f2bf(v); }
    #pragma unroll
    for (int j = 0; j < 4; ++j) { float v = c[j] > 0.f ? c[j] : 0.f; o[4 + j] = (short)f2bf(v); }
    *((short8*)(xb + (size_t)m * H_) + tid) = o;
  } else {
    int b = m - M_;
    const f32x4* s = (const f32x4*)(ehid + (size_t)b * H_) + tid * 2;
    f32x4 a = s[0], c = s[1];
    short8 o;
    #pragma unroll
    for (int j = 0; j < 4; ++j) o[j] = (short)f2bf(a[j]);
    #pragma unroll
    for (int j = 0; j < 4; ++j) o[4 + j] = (short)f2bf(c[j]);
    *((short8*)(hb + (size_t)b * H_) + tid) = o;
  }
}

// ---------------- 128x128 bf16 MFMA GEMM, K=1024, BK=64 ----------------
// C[m][n] = sum_k A[m][k]*B[n][k] + bias[n].  Row tiles on blockIdx.x (fastest)
// so co-resident blocks share B column tiles -> B fetched ~once from HBM.
__global__ __launch_bounds__(256, 2)
void k_gemm(const short* __restrict__ A, const short* __restrict__ Bm,
            const float* __restrict__ bias, float* __restrict__ C,
            float* __restrict__ sumexp, int N, int do_exp) {
  __shared__ short As[128 * 64];
  __shared__ short Bs[128 * 64];
  const int tid = threadIdx.x;
  const int bm = blockIdx.x, bn = blockIdx.y;   // row tiles fastest-varying
  const int w = tid >> 6, l = tid & 63;
  const int wm = (w >> 1) * 64, wn = (w & 1) * 64;
  f32x4 acc[4][4] = {};
  const short* Ab = A + (size_t)(bm * 128) * 1024;
  const short* Bb = Bm + (size_t)(bn * 128) * 1024;

  for (int kt = 0; kt < 1024; kt += 64) {
    #pragma unroll
    for (int i = 0; i < 4; ++i) {
      int g = i * 256 + tid, r = g >> 3, cp = g & 7, c = cp ^ (r & 7);
      async16(Ab + r * 1024 + kt + c * 8, &As[g * 8]);
    }
    #pragma unroll
    for (int i = 0; i < 4; ++i) {
      int g = i * 256 + tid, r = g >> 3, cp = g & 7, c = cp ^ (r & 7);
      async16(Bb + r * 1024 + kt + c * 8, &Bs[g * 8]);
    }
    __syncthreads();
    #pragma unroll
    for (int ks = 0; ks < 2; ++ks) {
      short8 af[4], bf[4];
      #pragma unroll
      for (int mi = 0; mi < 4; ++mi) {
        int row = wm + mi * 16 + (l & 15);
        int cp = (ks * 4 + (l >> 4)) ^ (row & 7);
        af[mi] = *(const short8*)&As[row * 64 + cp * 8];
      }
      #pragma unroll
      for (int ni = 0; ni < 4; ++ni) {
        int row = wn + ni * 16 + (l & 15);
        int cp = (ks * 4 + (l >> 4)) ^ (row & 7);
        bf[ni] = *(const short8*)&Bs[row * 64 + cp * 8];
      }
      #pragma unroll
      for (int mi = 0; mi < 4; ++mi)
        #pragma unroll
        for (int ni = 0; ni < 4; ++ni)
          acc[mi][ni] = __builtin_amdgcn_mfma_f32_16x16x32_bf16(af[mi], bf[ni], acc[mi][ni], 0, 0, 0);
    }
    __syncthreads();
  }

  // C/D layout: col = lane&15, row = (lane>>4)*4 + reg
  const int row0 = bm * 128 + wm + (l >> 4) * 4;
  const int col0 = bn * 128 + wn + (l & 15);
  if (!do_exp) {
    #pragma unroll
    for (int mi = 0; mi < 4; ++mi)
      #pragma unroll
      for (int ni = 0; ni < 4; ++ni) {
        int col = col0 + ni * 16;
        float bv = bias[col];
        #pragma unroll
        for (int rg = 0; rg < 4; ++rg)
          C[(size_t)(row0 + mi * 16 + rg) * N + col] = acc[mi][ni][rg] + bv;
      }
  } else {
    #pragma unroll
    for (int mi = 0; mi < 4; ++mi) {
      float rs[4] = {0.f, 0.f, 0.f, 0.f};
      #pragma unroll
      for (int ni = 0; ni < 4; ++ni) {
        int col = col0 + ni * 16;
        float bv = bias[col];
        #pragma unroll
        for (int rg = 0; rg < 4; ++rg) {
          float v = acc[mi][ni][rg] + bv;
          C[(size_t)(row0 + mi * 16 + rg) * N + col] = v;
          rs[rg] += __expf(v);
        }
      }
      #pragma unroll
      for (int rg = 0; rg < 4; ++rg) {
        float v = rs[rg];
        #pragma unroll
        for (int off = 1; off < 16; off <<= 1) v += __shfl_xor(v, off, 64);
        if ((l & 15) == 0) atomicAdd(&sumexp[row0 + mi * 16 + rg], v);
      }
    }
  }
}

// ---------------- persistent GRU: all 32 steps in one launch ----------------
// 64 blocks x 256 threads, 1 block/CU (LDS 128KB) -> co-residency guaranteed.
// Block bg owns j-strip [bg*16, bg*16+16): W_hh slice (48x1024 bf16) resident in
// LDS for all steps; h_f32 for the strip lives in registers. Per step: stage
// h_bf16 (64x1024) in double-buffered K=128 tiles, MFMA all 3 gates, fused gate
// epilogue, ping-pong h_bf16, grid barrier (device-scope counter + fences).
__device__ __forceinline__ void stageA(const short* __restrict__ hin, int kt,
                                       short* buf, int tid) {
  #pragma unroll
  for (int i = 0; i < 4; ++i) {
    int g = i * 256 + tid;                 // 1024 granules = 64 rows x 16
    int sub = g >> 9, gg = g & 511;        // two K=64 sub-tiles
    int r = gg >> 3, cp = gg & 7, c = cp ^ (r & 7);
    async16(hin + (size_t)r * 1024 + kt * 128 + sub * 64 + c * 8, &buf[g * 8]);
  }
}

__global__ __launch_bounds__(256, 1)
void k_gru_persist(const short* __restrict__ Whh, const float* __restrict__ bhh,
                   const float* __restrict__ gi, const float* __restrict__ ehid,
                   short* __restrict__ hb0, short* __restrict__ hb1,
                   short* __restrict__ hs, float* __restrict__ hfin,
                   unsigned* __restrict__ barcnt) {
  __shared__ short Wlds[16 * 48 * 64];   // 96 KB: 16 K64-tiles x 48 rows x 64
  __shared__ short As[2][2 * 64 * 64];   // 32 KB: double-buffered K=128 h tile
  const int tid = threadIdx.x;
  const int bg = blockIdx.x;
  const int j0 = bg * 16;
  const int w = tid >> 6, l = tid & 63;

  // load resident W_hh slice: 6144 granules of 16B, XOR-swizzled like As
  #pragma unroll
  for (int i = 0; i < 24; ++i) {
    int idx = i * 256 + tid;
    int tile = idx / 384, rem = idx % 384;
    int r = rem >> 3, cp = rem & 7, c = cp ^ (r & 7);
    int gate = r >> 4, jr = r & 15;
    async16(Whh + ((size_t)(gate * 1024 + j0 + jr)) * 1024 + tile * 64 + c * 8,
            &Wlds[idx * 8]);
  }

  // per-thread h_f32: b = b0+rg, j = jj
  const int jj = j0 + (l & 15);
  const int b0 = w * 16 + (l >> 4) * 4;
  float hreg[4];
  #pragma unroll
  for (int rg = 0; rg < 4; ++rg) hreg[rg] = ehid[(size_t)(b0 + rg) * H_ + jj];
  const float bh_r = bhh[jj], bh_z = bhh[1024 + jj], bh_n = bhh[2048 + jj];

  for (int t = 0; t < T_; ++t) {
    const short* hin = (t & 1) ? hb1 : hb0;
    short* hout      = (t & 1) ? hb0 : hb1;
    stageA(hin, 0, As[0], tid);
    f32x4 acc[3] = {};
    for (int kt = 0; kt < 8; ++kt) {
      __syncthreads();                       // buf[kt&1] ready (drains vmcnt)
      if (kt < 7) stageA(hin, kt + 1, As[(kt + 1) & 1], tid);
      const short* buf = As[kt & 1];
      #pragma unroll
      for (int sub = 0; sub < 2; ++sub) {
        int kt64 = kt * 2 + sub;
        #pragma unroll
        for (int ks = 0; ks < 2; ++ks) {
          int arow = w * 16 + (l & 15);
          int acp = (ks * 4 + (l >> 4)) ^ (arow & 7);
          short8 af = *(const short8*)&buf[sub * 4096 + arow * 64 + acp * 8];
          #pragma unroll
          for (int ga = 0; ga < 3; ++ga) {
            int brow = ga * 16 + (l & 15);
            int bcp = (ks * 4 + (l >> 4)) ^ (brow & 7);
            short8 bfr = *(const short8*)&Wlds[kt64 * 3072 + brow * 64 + bcp * 8];
            acc[ga] = __builtin_amdgcn_mfma_f32_16x16x32_bf16(af, bfr, acc[ga], 0, 0, 0);
          }
        }
      }
    }
    // fused gate epilogue
    #pragma unroll
    for (int rg = 0; rg < 4; ++rg) {
      const float* gir = gi + ((size_t)(t * 64) + b0 + rg) * 3072;
      float r = gir[jj] + acc[0][rg] + bh_r;
      r = 1.f / (1.f + __expf(-r));
      float z = gir[1024 + jj] + acc[1][rg] + bh_z;
      z = 1.f / (1.f + __expf(-z));
      float n = tanhf(gir[2048 + jj] + r * (acc[2][rg] + bh_n));
      float hn = (1.f - z) * n + z * hreg[rg];
      hreg[rg] = hn;
      short hbv = (short)f2bf(hn);
      hout[(size_t)(b0 + rg) * H_ + jj] = hbv;
      hs[((size_t)(b0 + rg) * T_ + t) * H_ + jj] = hbv;
    }
    if (t == T_ - 1) {
      #pragma unroll
      for (int rg = 0; rg < 4; ++rg) hfin[(size_t)(b0 + rg) * H_ + jj] = hreg[rg];
      break;                                  // no barrier after last step
    }
    // grid barrier: release h writes, wait all 64 blocks, acquire
    __syncthreads();
    if (tid == 0) {
      __threadfence();
      __hip_atomic_fetch_add(barcnt, 1u, __ATOMIC_RELEASE, __HIP_MEMORY_SCOPE_AGENT);
      while (__hip_atomic_load(barcnt, __ATOMIC_ACQUIRE, __HIP_MEMORY_SCOPE_AGENT)
             < (unsigned)(GRUB * (t + 1))) {}
      __threadfence();
    }
    __syncthreads();
  }
}

// ---------------- logsumexp finalize ----------------
__global__ void k_lse(float* s) {
  int i = blockIdx.x * 256 + threadIdx.x;
  if (i < M_) s[i] = logf(s[i]);
}

__global__ void k_sub(float* __restrict__ out, const float* __restrict__ lse) {
  size_t vid = (size_t)blockIdx.x * 256 + threadIdx.x;
  int r = (int)(vid / (V_ / 4));
  float ls = lse[r];
  f32x4* p = (f32x4*)out + vid;
  f32x4 v = *p;
  v[0] -= ls; v[1] -= ls; v[2] -= ls; v[3] -= ls;
  *p = v;
}

extern "C" void kernel_launch(void* const* d_in, const int* in_sizes, int n_in,
                              void* d_out, int out_size, void* d_ws, size_t ws_size,
                              hipStream_t stream) {
  const float* ehid = (const float*)d_in[1];
  const int*   tgt  = (const int*)d_in[3];
  const int*   sos  = (const int*)d_in[4];
  const float* emb  = (const float*)d_in[6];
  const float* Wih  = (const float*)d_in[7];
  const float* Whh  = (const float*)d_in[8];
  const float* bih  = (const float*)d_in[9];
  const float* bhh  = (const float*)d_in[10];
  const float* outW = (const float*)d_in[11];
  const float* outb = (const float*)d_in[12];
  float* out = (float*)d_out;

  // workspace carve-out
  char* ws = (char*)d_ws;
  size_t off = 0;
  auto alloc = [&](size_t bytes) -> void* {
    void* p = ws + off;
    off = (off + bytes + 255) & ~(size_t)255;
    return p;
  };
  short* outW_b = (short*)alloc((size_t)V_ * H_ * 2);       // 65.5 MB
  short* Wih_b  = (short*)alloc((size_t)3 * H_ * H_ * 2);   // 6.3 MB
  short* Whh_b  = (short*)alloc((size_t)3 * H_ * H_ * 2);   // 6.3 MB
  short* xb     = (short*)alloc((size_t)M_ * H_ * 2);       // 4.2 MB
  float* gi     = (float*)alloc((size_t)M_ * 3 * H_ * 4);   // 25.2 MB
  short* hs     = (short*)alloc((size_t)M_ * H_ * 2);       // 4.2 MB
  short* hb0    = (short*)alloc((size_t)B_ * H_ * 2);
  short* hb1    = (short*)alloc((size_t)B_ * H_ * 2);
  float* sume   = (float*)alloc((size_t)M_ * 4);
  unsigned* barcnt = (unsigned*)alloc(256);

  // weight conversions f32 -> bf16
  k_convert<<<V_ * H_ / 8 / 256, 256, 0, stream>>>(outW, outW_b, V_ * H_ / 8);
  k_convert<<<3 * H_ * H_ / 8 / 256, 256, 0, stream>>>(Wih, Wih_b, 3 * H_ * H_ / 8);
  k_convert<<<3 * H_ * H_ / 8 / 256, 256, 0, stream>>>(Whh, Whh_b, 3 * H_ * H_ / 8);

  // zero barrier counter + sumexp
  hipMemsetAsync(barcnt, 0, 4, stream);
  hipMemsetAsync(sume, 0, M_ * 4, stream);

  // embedding gather + relu + h0(bf16) init
  k_embed<<<M_ + B_, 128, 0, stream>>>(emb, tgt, sos, ehid, xb, hb0);

  // gi = relu(emb[tokens]) @ W_ih^T + b_ih   (M=2048, N=3072)
  dim3 g1(M_ / 128, 3 * H_ / 128);
  k_gemm<<<g1, 256, 0, stream>>>(xb, Wih_b, bih, gi, nullptr, 3 * H_, 0);

  // GRU recurrence: one persistent launch for all 32 steps
  k_gru_persist<<<GRUB, 256, 0, stream>>>(Whh_b, bhh, gi, ehid, hb0, hb1, hs,
                                          out + (size_t)B_ * T_ * V_, barcnt);

  // logits = hs @ out_W^T + out_b, fused exp-row-sum (M=2048, N=32000)
  dim3 g2(M_ / 128, V_ / 128);
  k_gemm<<<g2, 256, 0, stream>>>(hs, outW_b, outb, out, sume, V_, 1);

  // log_probs = logits - log(sum exp)
  k_lse<<<8, 256, 0, stream>>>(sume);
  k_sub<<<(int)((size_t)B_ * T_ * V_ / 4 / 256), 256, 0, stream>>>(out, sume);
}